// Round 4
// baseline (946.249 us; speedup 1.0000x reference)
//
#include <hip/hip_runtime.h>
#include <hip/hip_fp16.h>

// N=1024, F=22, T=1000, H=64, gates 4H=256
// R14: two-phase checkerboard — anti-phase MFMA vs gate-VALU across roles.
// R12/R13 showed MfmaUtil(780cy) + VALUBusy(878cy) = tick(1688cy): the single
// barrier per tick convoys all waves through MFMA-phase then gate-phase with
// ZERO pipe overlap (setprio null on lockstep, as in learn_hip m190).
// Fix: 2 barriers/interval, roles in anti-phase:
//   P1(n): L0 gates(n-1)+wr, L1 gates(n-2)+wr, L2 MFMA(n-3), ST writes x(n)
//   P2(n): L0 MFMA(n),       L1 MFMA(n-1),     L2 gates(n-3)+wr
// Matrix pipe busy in BOTH phases (16 MFMA in P1, 28 in P2) while the other
// roles' gate VALU runs underneath. Accumulators live in regs across phases.
// Dependency/slot audit (ring 8, slots keyed by timestep t):
//   x(t)->in0 slot t&7 c0..21 [P1(t)];  h0rec(t)->in0 slot (t+1)&7 c32..95 [P1(t+1)]
//   h0fwd(t)->in1 slot t&7 c0..63 [P1(t+1)]; h1rec(t)->in1 slot (t+1)&7 c64..127 [P1(t+2)]
//   h1fwd(t)->in2 slot t&7 c0..63 [P1(t+2)]; h2rec(t)->in2 slot (t+1)&7 c64..127 [P2(t+3)]
//   readers: L0 MFMA(t): in0 slot t&7 @P2(t); L1 MFMA(t): in1 slot t&7 @P2(t+1);
//            L2 MFMA(t): in2 slot t&7 @P1(t+3).  All edges >=1 barrier; all
//   same-slot writes col-disjoint; overwrite distance >= 7 intervals.
// Guards: L0 M n<=999 / G 1<=n<=1000; L1 M 1<=n<=1000 / G 2<=n<=1001;
//         L2 3<=n<=1002 (final h2 @ P2(1002) -> fcA). Loop 126*8=1008 intervals,
//         exactly 2 barriers each for all 14 waves.
// 896 thr = 14 waves: 0-3 L2, 4-7 L1, 8-11 L0, 12-13 stager.
#define TT 1000
#define FF 22
#define HH 64
#define BB 4
#define NBLK 256
#define S0 112
#define S1 144
#define SL0 (4 * S0)
#define SL1 (4 * S1)

typedef _Float16 half8 __attribute__((ext_vector_type(8)));
typedef float float4v __attribute__((ext_vector_type(4)));

__device__ __forceinline__ float sel4(const float4v a, int q) {
    float lo = (q & 2) ? a[2] : a[0];
    float hi = (q & 2) ? a[3] : a[1];
    return (q & 1) ? hi : lo;
}

// Fused LSTM gate math: 5 exp + 2 rcp (R13, verified absmax 2.44e-4).
__device__ __forceinline__ float gate_fused(const float z[4], float& c) {
    float e0 = __expf(-z[0]);
    float e1 = __expf(-z[1]);
    float e2 = __expf(2.0f * z[2]);
    float d1 = 1.0f + e1;
    float d2 = (1.0f + e0) * (1.0f + e2);
    float r  = __builtin_amdgcn_rcpf(d1 * d2);
    float f  = d2 * r;
    float ig = (e2 - 1.0f) * (d1 * r);
    float cc = __builtin_fmaf(f, c, ig);
    c = cc;
    float e3 = __expf(-z[3]);
    float e4 = __expf(2.0f * cc);
    float r2 = __builtin_amdgcn_rcpf((1.0f + e3) * (1.0f + e4));
    return (e4 - 1.0f) * r2;
}

// phase boundary: LDS release + barrier + compiler fence both sides
#define SYNC() do { asm volatile("s_waitcnt lgkmcnt(0)" ::: "memory"); \
                    __builtin_amdgcn_s_barrier(); \
                    asm volatile("" ::: "memory"); } while (0)

extern "C" __global__ void __launch_bounds__(896, 1)
lstm_fused(const float* __restrict__ x,
           const float* __restrict__ Wih0, const float* __restrict__ Whh0,
           const float* __restrict__ bih0, const float* __restrict__ bhh0,
           const float* __restrict__ Wih1, const float* __restrict__ Whh1,
           const float* __restrict__ bih1, const float* __restrict__ bhh1,
           const float* __restrict__ Wih2, const float* __restrict__ Whh2,
           const float* __restrict__ bih2, const float* __restrict__ bhh2,
           const float* __restrict__ w0, const float* __restrict__ b0,
           const float* __restrict__ w1, const float* __restrict__ b1,
           const float* __restrict__ w2, const float* __restrict__ b2,
           const float* __restrict__ w3, const float* __restrict__ b3,
           const float* __restrict__ g0, const float* __restrict__ be0,
           const float* __restrict__ m0, const float* __restrict__ v0,
           const float* __restrict__ g1, const float* __restrict__ be1,
           const float* __restrict__ m1, const float* __restrict__ v1,
           const float* __restrict__ g2, const float* __restrict__ be2,
           const float* __restrict__ m2, const float* __restrict__ v2,
           float* __restrict__ out)
{
    __shared__ __align__(16) _Float16 in0[8 * SL0];
    __shared__ __align__(16) _Float16 in1[8 * SL1];
    __shared__ __align__(16) _Float16 in2[8 * SL1];
    __shared__ float fcA[BB * 64];
    __shared__ float fcB[BB * 64];
    __shared__ float fcW[54 * 65];
    __shared__ float fcP[5 * 64];

    const int tid  = threadIdx.x;
    const int wv   = tid >> 6;      // 0..13
    const int role = wv >> 2;       // 0=L2, 1=L1, 2=L0, 3=stager
    const int w4   = wv & 3;
    const int l    = tid & 63;
    const int q    = l >> 4;
    const int l15  = l & 15;
    const int u    = 16 * w4 + l15;
    const int b    = q;
    const int n0   = blockIdx.x * BB;

    for (int i = tid; i < 8 * SL0; i += 896) in0[i] = (_Float16)0.0f;
    for (int i = tid; i < 8 * SL1; i += 896) in1[i] = (_Float16)0.0f;
    for (int i = tid; i < 8 * SL1; i += 896) in2[i] = (_Float16)0.0f;

    // ---- weight B-fragments: one unit per wave ----
    half8 wf[4][4];
    float4v biasC[4];
    if (role == 2) {                 // layer 0
#pragma unroll
        for (int g = 0; g < 4; ++g) {
            const int row = 64 * g + u;
#pragma unroll
            for (int kt = 0; kt < 3; ++kt) {
                half8 h{};
#pragma unroll
                for (int j = 0; j < 8; ++j) {
                    const int k = 32 * kt + 8 * q + j;
                    float val = 0.0f;
                    if (k < 32) { if (k < FF) val = Wih0[row * FF + k]; }
                    else        { val = Whh0[row * HH + (k - 32)]; }
                    h[j] = (_Float16)val;
                }
                wf[g][kt] = h;
            }
            float bv = bih0[row] + bhh0[row];
            biasC[g] = float4v{bv, bv, bv, bv};
        }
    } else if (role < 2) {           // 0 -> layer 2, 1 -> layer 1
        const float* Wih = role ? Wih1 : Wih2;
        const float* Whh = role ? Whh1 : Whh2;
        const float* bih = role ? bih1 : bih2;
        const float* bhh = role ? bhh1 : bhh2;
#pragma unroll
        for (int g = 0; g < 4; ++g) {
            const int row = 64 * g + u;
#pragma unroll
            for (int kt = 0; kt < 4; ++kt) {
                half8 h{};
#pragma unroll
                for (int j = 0; j < 8; ++j) {
                    const int k = 32 * kt + 8 * q + j;
                    h[j] = (_Float16)((k < 64) ? Wih[row * HH + k] : Whh[row * HH + (k - 64)]);
                }
                wf[g][kt] = h;
            }
            float bv = bih[row] + bhh[row];
            biasC[g] = float4v{bv, bv, bv, bv};
        }
    }

    // ---- x staging lanes: waves 12-13, 88 items ----
    const int  st  = tid - 768;
    const bool xok = (role == 3) && (st >= 0) && (st < BB * FF);
    const int  xb  = xok ? (st / FF) : 0;
    const int  xf  = xok ? (st - xb * FF) : 0;
    const float* xp = x + ((size_t)(n0 + xb) * FF + xf) * TT;

    __syncthreads();                 // zero-init complete

    float xA = xok ? xp[0] : 0.f;    // x(n) to write at P1(n)
    float xB = xok ? xp[1] : 0.f;    // depth-2 prefetch

    const int arow = (role == 2) ? ((l15 & 3) * S0 + q * 8) : ((l15 & 3) * S1 + q * 8);
    float c = 0.f;
    float4v acc[4] = {};             // carried across the P1/P2 boundary

    // ============ main loop: 126*8 = 1008 intervals, 2 barriers each ============
    for (int k = 0; k < 126; ++k) {
#pragma unroll
        for (int s = 0; s < 8; ++s) {
            const int n = 8 * k + s;

            // ================= P1 =================
            SYNC();
            if (role == 3) {         // stager: write x(n), prefetch x(n+2)
                if (n <= TT - 1) {
                    if (xok) in0[s * SL0 + xb * S0 + xf] = (_Float16)xA;
                    xA = xB;
                    if (xok) {
                        int tn = n + 2; if (tn > TT - 1) tn = TT - 1;
                        xB = xp[tn];
                    }
                }
            } else if (role == 2) {  // L0 gates(t = n-1)
                if (n >= 1 && n <= TT) {
                    float z[4];
#pragma unroll
                    for (int g = 0; g < 4; ++g) z[g] = sel4(acc[g], q);
                    float h = gate_fused(z, c);
                    _Float16 hf = (_Float16)h;
                    in0[s * SL0 + b * S0 + 32 + u]          = hf; // rec -> slot n&7
                    in1[((s + 7) & 7) * SL1 + b * S1 + u]   = hf; // fwd -> slot (n-1)&7
                }
            } else if (role == 1) {  // L1 gates(t = n-2)
                if (n >= 2 && n <= TT + 1) {
                    float z[4];
#pragma unroll
                    for (int g = 0; g < 4; ++g) z[g] = sel4(acc[g], q);
                    float h = gate_fused(z, c);
                    _Float16 hf = (_Float16)h;
                    in1[((s + 7) & 7) * SL1 + b * S1 + 64 + u] = hf; // rec -> slot (n-1)&7
                    in2[((s + 6) & 7) * SL1 + b * S1 + u]      = hf; // fwd -> slot (n-2)&7
                }
            } else {                 // L2 MFMA(t = n-3)
                if (n >= 3 && n <= TT + 2) {
                    const _Float16* rd = in2 + ((s + 5) & 7) * SL1;
                    half8 a0 = *(const half8*)(rd + arow);
                    half8 a1 = *(const half8*)(rd + arow + 32);
                    half8 a2 = *(const half8*)(rd + arow + 64);
                    half8 a3 = *(const half8*)(rd + arow + 96);
#pragma unroll
                    for (int g = 0; g < 4; ++g)
                        acc[g] = __builtin_amdgcn_mfma_f32_16x16x32_f16(a0, wf[g][0], biasC[g], 0, 0, 0);
#pragma unroll
                    for (int g = 0; g < 4; ++g)
                        acc[g] = __builtin_amdgcn_mfma_f32_16x16x32_f16(a1, wf[g][1], acc[g], 0, 0, 0);
#pragma unroll
                    for (int g = 0; g < 4; ++g)
                        acc[g] = __builtin_amdgcn_mfma_f32_16x16x32_f16(a2, wf[g][2], acc[g], 0, 0, 0);
#pragma unroll
                    for (int g = 0; g < 4; ++g)
                        acc[g] = __builtin_amdgcn_mfma_f32_16x16x32_f16(a3, wf[g][3], acc[g], 0, 0, 0);
                }
            }

            // ================= P2 =================
            SYNC();
            if (role == 2) {         // L0 MFMA(t = n)
                if (n <= TT - 1) {
                    const _Float16* rd = in0 + s * SL0;
                    half8 a0 = *(const half8*)(rd + arow);
                    half8 a1 = *(const half8*)(rd + arow + 32);
                    half8 a2 = *(const half8*)(rd + arow + 64);
#pragma unroll
                    for (int g = 0; g < 4; ++g)
                        acc[g] = __builtin_amdgcn_mfma_f32_16x16x32_f16(a0, wf[g][0], biasC[g], 0, 0, 0);
#pragma unroll
                    for (int g = 0; g < 4; ++g)
                        acc[g] = __builtin_amdgcn_mfma_f32_16x16x32_f16(a1, wf[g][1], acc[g], 0, 0, 0);
#pragma unroll
                    for (int g = 0; g < 4; ++g)
                        acc[g] = __builtin_amdgcn_mfma_f32_16x16x32_f16(a2, wf[g][2], acc[g], 0, 0, 0);
                }
            } else if (role == 1) {  // L1 MFMA(t = n-1)
                if (n >= 1 && n <= TT) {
                    const _Float16* rd = in1 + ((s + 7) & 7) * SL1;
                    half8 a0 = *(const half8*)(rd + arow);
                    half8 a1 = *(const half8*)(rd + arow + 32);
                    half8 a2 = *(const half8*)(rd + arow + 64);
                    half8 a3 = *(const half8*)(rd + arow + 96);
#pragma unroll
                    for (int g = 0; g < 4; ++g)
                        acc[g] = __builtin_amdgcn_mfma_f32_16x16x32_f16(a0, wf[g][0], biasC[g], 0, 0, 0);
#pragma unroll
                    for (int g = 0; g < 4; ++g)
                        acc[g] = __builtin_amdgcn_mfma_f32_16x16x32_f16(a1, wf[g][1], acc[g], 0, 0, 0);
#pragma unroll
                    for (int g = 0; g < 4; ++g)
                        acc[g] = __builtin_amdgcn_mfma_f32_16x16x32_f16(a2, wf[g][2], acc[g], 0, 0, 0);
#pragma unroll
                    for (int g = 0; g < 4; ++g)
                        acc[g] = __builtin_amdgcn_mfma_f32_16x16x32_f16(a3, wf[g][3], acc[g], 0, 0, 0);
                }
            } else if (role == 0) {  // L2 gates(t = n-3)
                if (n >= 3 && n <= TT + 2) {
                    float z[4];
#pragma unroll
                    for (int g = 0; g < 4; ++g) z[g] = sel4(acc[g], q);
                    float h = gate_fused(z, c);
                    if (n != TT + 2) {
                        in2[((s + 6) & 7) * SL1 + b * S1 + 64 + u] = (_Float16)h; // rec -> slot (n-2)&7
                    } else {
                        fcA[b * 64 + u] = h;              // final h2(999), fp32
                    }
                }
            }
        }
    }

    __syncthreads();

    // ================= FC head (fp32) =================
    for (int i = tid; i < 54 * 64; i += 896) fcW[(i >> 6) * 65 + (i & 63)] = w0[i];
    for (int i = tid; i < 54; i += 896) {
        fcP[i] = b0[i]; fcP[64 + i] = g0[i]; fcP[128 + i] = be0[i];
        fcP[192 + i] = m0[i]; fcP[256 + i] = v0[i];
    }
    __syncthreads();
    for (int idx = tid; idx < BB * 54; idx += 896) {
        const int bb = idx / 54, j = idx - bb * 54;
        float s = fcP[j];
        for (int k = 0; k < 64; ++k) s += fcW[j * 65 + k] * fcA[bb * 64 + k];
        s = (s - fcP[192 + j]) * rsqrtf(fcP[256 + j] + 1e-5f) * fcP[64 + j] + fcP[128 + j];
        fcB[bb * 64 + j] = fmaxf(s, 0.0f);
    }
    __syncthreads();

    for (int i = tid; i < 44 * 54; i += 896) fcW[(i / 54) * 55 + (i % 54)] = w1[i];
    for (int i = tid; i < 44; i += 896) {
        fcP[i] = b1[i]; fcP[64 + i] = g1[i]; fcP[128 + i] = be1[i];
        fcP[192 + i] = m1[i]; fcP[256 + i] = v1[i];
    }
    __syncthreads();
    for (int idx = tid; idx < BB * 44; idx += 896) {
        const int bb = idx / 44, j = idx - bb * 44;
        float s = fcP[j];
        for (int k = 0; k < 54; ++k) s += fcW[j * 55 + k] * fcB[bb * 64 + k];
        s = (s - fcP[192 + j]) * rsqrtf(fcP[256 + j] + 1e-5f) * fcP[64 + j] + fcP[128 + j];
        fcA[bb * 64 + j] = fmaxf(s, 0.0f);
    }
    __syncthreads();

    for (int i = tid; i < 24 * 44; i += 896) fcW[(i / 44) * 45 + (i % 44)] = w2[i];
    for (int i = tid; i < 24; i += 896) {
        fcP[i] = b2[i]; fcP[64 + i] = g2[i]; fcP[128 + i] = be2[i];
        fcP[192 + i] = m2[i]; fcP[256 + i] = v2[i];
    }
    __syncthreads();
    for (int idx = tid; idx < BB * 24; idx += 896) {
        const int bb = idx / 24, j = idx - bb * 24;
        float s = fcP[j];
        for (int k = 0; k < 44; ++k) s += fcW[j * 45 + k] * fcA[bb * 64 + k];
        s = (s - fcP[192 + j]) * rsqrtf(fcP[256 + j] + 1e-5f) * fcP[64 + j] + fcP[128 + j];
        fcB[bb * 64 + j] = fmaxf(s, 0.0f);
    }
    __syncthreads();

    for (int i = tid; i < 4 * 24; i += 896) fcW[(i / 24) * 25 + (i % 24)] = w3[i];
    for (int i = tid; i < 4; i += 896) fcP[i] = b3[i];
    __syncthreads();
    for (int idx = tid; idx < BB * 4; idx += 896) {
        const int bb = idx / 4, j = idx - bb * 4;
        float s = fcP[j];
        for (int k = 0; k < 24; ++k) s += fcW[j * 25 + k] * fcB[bb * 64 + k];
        out[(size_t)(n0 + bb) * 4 + j] = s;
    }
}

extern "C" void kernel_launch(void* const* d_in, const int* in_sizes, int n_in,
                              void* d_out, int out_size, void* d_ws, size_t ws_size,
                              hipStream_t stream) {
    const float* p[33];
    for (int i = 0; i < 33; ++i) p[i] = (const float*)d_in[i];
    lstm_fused<<<NBLK, 896, 0, stream>>>(
        p[0],
        p[1], p[2], p[3], p[4],
        p[5], p[6], p[7], p[8],
        p[9], p[10], p[11], p[12],
        p[13], p[14], p[15], p[16], p[17], p[18], p[19], p[20],
        p[21], p[22], p[23], p[24],
        p[25], p[26], p[27], p[28],
        p[29], p[30], p[31], p[32],
        (float*)d_out);
}